// Round 6
// baseline (340.185 us; speedup 1.0000x reference)
//
#include <hip/hip_runtime.h>
#include <math.h>

#define CHUNK 256      // simplices per ect block
#define FPS 32768.0f   // fixed-point scale 2^15 for transition sums

// K1: nh[n][t] = x[n].v[:,t]. One thread per node, 32 outputs via float4.
__global__ __launch_bounds__(256) void nh_kernel(const float* __restrict__ x,
    const float* __restrict__ v, float* __restrict__ nh, int N) {
  __shared__ float vs[96];
  int tid = threadIdx.x;
  if (tid < 96) vs[tid] = v[tid];
  __syncthreads();
  int n = blockIdx.x * 256 + tid;
  if (n >= N) return;
  float x0 = x[3 * n], x1 = x[3 * n + 1], x2 = x[3 * n + 2];
  float4* row = (float4*)(nh + (size_t)n * 32);
#pragma unroll
  for (int i = 0; i < 8; ++i) {
    float4 r;
    r.x = fmaf(x0, vs[4 * i + 0], fmaf(x1, vs[32 + 4 * i + 0], x2 * vs[64 + 4 * i + 0]));
    r.y = fmaf(x0, vs[4 * i + 1], fmaf(x1, vs[32 + 4 * i + 1], x2 * vs[64 + 4 * i + 1]));
    r.z = fmaf(x0, vs[4 * i + 2], fmaf(x1, vs[32 + 4 * i + 2], x2 * vs[64 + 4 * i + 2]));
    r.w = fmaf(x0, vs[4 * i + 3], fmaf(x1, vs[32 + 4 * i + 3], x2 * vs[64 + 4 * i + 3]));
    row[i] = r;
  }
}

// K2: raw-order saturation-split ECT with direct global int atomics, plus
// fused last-block finisher (prefix over bins + max-normalize + output).
// Thread (srow, t): simplices start+srow+8k, theta = t. Half-wave lanes hit
// 32 distinct theta addresses -> no intra-wave same-address serialization.
// All accumulation is integer atomicAdd -> order-independent -> deterministic.
__global__ __launch_bounds__(256) void ect_kernel(const float* __restrict__ nh,
    const int* __restrict__ ei, const int* __restrict__ face,
    const int* __restrict__ batch, const float* __restrict__ lin,
    const int* __restrict__ scale_p, int* __restrict__ gcnt,
    int* __restrict__ gacc, int* __restrict__ done, float* __restrict__ out,
    int N, int E, int F, int M, int nblk) {
  int tid = threadIdx.x;
  int t = tid & 31, srow = tid >> 5;
  int start = blockIdx.x * CHUNK;
  int end = min(start + CHUNK, M);

  float scale = (float)scale_p[0];
  float lin0 = lin[0];
  float step = (lin[31] - lin0) * (1.f / 31.f);
  float istep = 1.f / step;
  float Cl = scale * step * 1.44269504088896f;  // log2-slope per bin
  float w = 13.f / (scale * step);              // transition half-width (bins)

  for (int m = start + srow; m < end; m += 8) {
    float h;
    int isn, g;
    if (m < N) {
      h = nh[m * 32 + t];
      g = batch[m];
      isn = 1;
    } else if (m < N + E) {
      int e = m - N;
      int n0 = ei[e], n1 = ei[E + e];
      h = fmaxf(nh[n0 * 32 + t], nh[n1 * 32 + t]);
      g = batch[n0];
      isn = -1;
    } else {
      int f = m - N - E;
      int n0 = face[f], n1 = face[F + f], n2 = face[2 * F + f];
      h = fmaxf(fmaxf(nh[n0 * 32 + t], nh[n1 * 32 + t]), nh[n2 * 32 + t]);
      g = batch[n0];
      isn = 1;
    }
    float kf = (h - lin0) * istep;
    int b0 = (int)ceilf(kf - w);
    int b1 = (int)floorf(kf + w);
    int fs = max(b1 + 1, 0);
    int gb = g << 10;
    if (fs <= 31) atomicAdd(&gcnt[gb + (fs << 5) + t], isn);
    float q = Cl * kf;
    float fsn = (float)isn;
    int blo = max(b0, 0), bhi = min(b1, 31);
    for (int b = blo; b <= bhi; ++b) {
      float e2 = __builtin_amdgcn_exp2f(fmaf(-Cl, (float)b, q));
      float val = fsn * __builtin_amdgcn_rcpf(1.f + e2);
      atomicAdd(&gacc[gb + (b << 5) + t], (int)rintf(val * FPS));
    }
  }

  // ---- fused finisher: last block to arrive does the epilogue ----
  __threadfence();
  __shared__ int amLast;
  if (tid == 0) amLast = (atomicAdd(done, 1) == nblk - 1);
  __syncthreads();
  if (!amLast) return;

  // 256 threads = (g = tid>>5, th = tid&31). Each thread owns one theta
  // column of one graph: serial prefix over 32 bins (values pipelined into
  // registers), fractional add, then cross-lane max within the 32-lane
  // theta group (same graph), normalize, write.
  int g = tid >> 5, th = tid & 31;
  int base = (g << 10) + th;
  float r[32];
  int runc = 0;
  float mx = -1e30f;
#pragma unroll
  for (int k = 0; k < 32; ++k) {
    int c = __hip_atomic_load(&gcnt[base + (k << 5)], __ATOMIC_RELAXED,
                              __HIP_MEMORY_SCOPE_AGENT);
    int a = __hip_atomic_load(&gacc[base + (k << 5)], __ATOMIC_RELAXED,
                              __HIP_MEMORY_SCOPE_AGENT);
    runc += c;
    r[k] = (float)runc + (float)a * (1.f / FPS);
    mx = fmaxf(mx, r[k]);
  }
#pragma unroll
  for (int off = 1; off < 32; off <<= 1) mx = fmaxf(mx, __shfl_xor(mx, off));
#pragma unroll
  for (int k = 0; k < 32; ++k)
    out[(g << 10) + (k << 5) + th] = r[k] / mx;
}

extern "C" void kernel_launch(void* const* d_in, const int* in_sizes, int n_in,
                              void* d_out, int out_size, void* d_ws, size_t ws_size,
                              hipStream_t stream) {
  const float* x     = (const float*)d_in[0];
  const float* v     = (const float*)d_in[1];
  const float* lin   = (const float*)d_in[2];
  const int*   ei    = (const int*)d_in[3];
  const int*   face  = (const int*)d_in[4];
  const int*   batch = (const int*)d_in[5];
  const int*   scale = (const int*)d_in[6];
  const int N = in_sizes[5];
  const int E = in_sizes[3] / 2;
  const int F = in_sizes[4] / 3;
  const int M = N + E + F;

  float* nh   = (float*)d_ws;                 // N*32 f32
  int*   gcnt = (int*)(nh + (size_t)N * 32);  // 8*1024
  int*   gacc = gcnt + 8 * 1024;              // 8*1024
  int*   done = gacc + 8 * 1024;              // 1 (+pad)

  hipMemsetAsync(gcnt, 0, (8 * 1024 * 2 + 64) * sizeof(int), stream);
  nh_kernel<<<(N + 255) / 256, 256, 0, stream>>>(x, v, nh, N);
  const int nblk = (M + CHUNK - 1) / CHUNK;
  ect_kernel<<<nblk, 256, 0, stream>>>(nh, ei, face, batch, lin, scale, gcnt,
                                       gacc, done, (float*)d_out, N, E, F, M,
                                       nblk);
}

// Round 7
// 58.040 us; speedup vs baseline: 5.8612x; 5.8612x over previous
//
#include <hip/hip_runtime.h>
#include <math.h>

#define CHUNK 512      // simplices per ect block
#define RSL 8          // reduction slices
#define FPS 32768.0f   // fixed-point scale 2^15 for transition sums

// K1: nh[n][t] = x[n].v[:,t]. One thread per node, 32 outputs via float4.
__global__ __launch_bounds__(256) void nh_kernel(const float* __restrict__ x,
    const float* __restrict__ v, float* __restrict__ nh, int N) {
  __shared__ float vs[96];
  int tid = threadIdx.x;
  if (tid < 96) vs[tid] = v[tid];
  __syncthreads();
  int n = blockIdx.x * 256 + tid;
  if (n >= N) return;
  float x0 = x[3 * n], x1 = x[3 * n + 1], x2 = x[3 * n + 2];
  float4* row = (float4*)(nh + (size_t)n * 32);
#pragma unroll
  for (int i = 0; i < 8; ++i) {
    float4 r;
    r.x = fmaf(x0, vs[4 * i + 0], fmaf(x1, vs[32 + 4 * i + 0], x2 * vs[64 + 4 * i + 0]));
    r.y = fmaf(x0, vs[4 * i + 1], fmaf(x1, vs[32 + 4 * i + 1], x2 * vs[64 + 4 * i + 1]));
    r.z = fmaf(x0, vs[4 * i + 2], fmaf(x1, vs[32 + 4 * i + 2], x2 * vs[64 + 4 * i + 2]));
    r.w = fmaf(x0, vs[4 * i + 3], fmaf(x1, vs[32 + 4 * i + 3], x2 * vs[64 + 4 * i + 3]));
    row[i] = r;
  }
}

// K2: raw-order saturation-split ECT. Block = (chunk c, theta-half hf).
// LDS histogram covers ALL 8 graphs for 16 thetas: [arr][g][bin][t16] = 32 KB.
// arr0 = saturated-region markers (int counts), arr1 = fixed-point transition
// sigmoid sums. LDS int atomics only (deterministic by associativity; the 16
// t16 lanes of each quarter-wave hit distinct addresses). Flush = plain
// coalesced int4 stores to partial[bid][8192] — no global atomics anywhere.
__global__ __launch_bounds__(256) void ect_kernel(const float* __restrict__ nh,
    const int* __restrict__ ei, const int* __restrict__ face,
    const int* __restrict__ batch, const float* __restrict__ lin,
    const int* __restrict__ scale_p, int* __restrict__ partial,
    int N, int E, int F, int M) {
  __shared__ alignas(16) int hist[8192];  // arr*4096 + g*512 + bin*16 + t16
  int tid = threadIdx.x;
  int bid = blockIdx.x;
  int c = bid >> 1, hf = bid & 1;
#pragma unroll
  for (int i = 0; i < 8; ++i)
    ((int4*)hist)[tid + 256 * i] = int4{0, 0, 0, 0};
  __syncthreads();

  int t16 = tid & 15, srow = tid >> 4;
  int tt = (hf << 4) + t16;               // global theta
  int start = c * CHUNK;
  int end = min(start + CHUNK, M);

  float scale = (float)scale_p[0];
  float lin0 = lin[0];
  float step = (lin[31] - lin0) * (1.f / 31.f);
  float istep = 1.f / step;
  float Cl = scale * step * 1.44269504088896f;  // log2-slope per bin
  float w = 13.f / (scale * step);              // transition half-width (bins)

  for (int m = start + srow; m < end; m += 16) {
    float h;
    int isn, g;
    if (m < N) {
      h = nh[(size_t)m * 32 + tt];
      g = batch[m];
      isn = 1;
    } else if (m < N + E) {
      int e = m - N;
      int n0 = ei[e], n1 = ei[E + e];
      h = fmaxf(nh[(size_t)n0 * 32 + tt], nh[(size_t)n1 * 32 + tt]);
      g = batch[n0];
      isn = -1;
    } else {
      int f = m - N - E;
      int n0 = face[f], n1 = face[F + f], n2 = face[2 * F + f];
      h = fmaxf(fmaxf(nh[(size_t)n0 * 32 + tt], nh[(size_t)n1 * 32 + tt]),
                nh[(size_t)n2 * 32 + tt]);
      g = batch[n0];
      isn = 1;
    }
    float kf = (h - lin0) * istep;
    int b0 = (int)ceilf(kf - w);
    int b1 = (int)floorf(kf + w);
    int fs = max(b1 + 1, 0);
    int gb = g << 9;
    if (fs <= 31) atomicAdd(&hist[gb + (fs << 4) + t16], isn);
    float q = Cl * kf;
    float fsn = (float)isn;
    int blo = max(b0, 0), bhi = min(b1, 31);
    for (int b = blo; b <= bhi; ++b) {
      float e2 = __builtin_amdgcn_exp2f(fmaf(-Cl, (float)b, q));
      float val = fsn * __builtin_amdgcn_rcpf(1.f + e2);
      atomicAdd(&hist[4096 + gb + (b << 4) + t16], (int)rintf(val * FPS));
    }
  }
  __syncthreads();
  int4* dst = (int4*)(partial + (size_t)bid * 8192);
  const int4* src = (const int4*)hist;
#pragma unroll
  for (int i = 0; i < 8; ++i)
    dst[tid + 256 * i] = src[tid + 256 * i];
}

// K3: tree reduce over chunks. cell cid = hf*8192 + (arr*4096+g*512+b*16+t16).
// Block (slice s, cid-group): sums c = s, s+RSL, ... -> part2[s][cid].
__global__ __launch_bounds__(256) void reduce_kernel(const int* __restrict__ partial,
    int* __restrict__ part2, int nchunk) {
  int bb = blockIdx.x;
  int s = bb >> 6, cg = bb & 63;
  int cid = cg * 256 + threadIdx.x;
  int hf = cid >> 13, j = cid & 8191;
  int sum = 0;
  for (int c = s; c < nchunk; c += RSL)
    sum += partial[(size_t)(c * 2 + hf) * 8192 + j];
  part2[s * 16384 + cid] = sum;
}

// K4: per-graph block: sum RSL slices, Hillis-Steele prefix of markers over
// bins, add fractional part, max over (bin,theta), normalize, write out.
__global__ __launch_bounds__(1024) void fin_kernel(const int* __restrict__ part2,
    float* __restrict__ out) {
  __shared__ float sP[32][33];
  __shared__ float wmax[16];
  int g = blockIdx.x, tid = threadIdx.x;
  int b = tid >> 5, t = tid & 31;
  int hf = t >> 4, t16 = t & 15;
  int jc = (hf << 13) + (g << 9) + (b << 4) + t16;  // marker cell
  int ja = jc + 4096;                               // transition cell
  int sc = 0, sa = 0;
#pragma unroll
  for (int s = 0; s < RSL; ++s) {
    sc += part2[s * 16384 + jc];
    sa += part2[s * 16384 + ja];
  }
  sP[b][t] = (float)sc;
  __syncthreads();
#pragma unroll
  for (int st = 1; st < 32; st <<= 1) {
    float add = (b >= st) ? sP[b - st][t] : 0.f;
    __syncthreads();
    sP[b][t] += add;
    __syncthreads();
  }
  float r = sP[b][t] + (float)sa * (1.f / FPS);
  float m = r;
#pragma unroll
  for (int off = 32; off > 0; off >>= 1) m = fmaxf(m, __shfl_down(m, off));
  if ((tid & 63) == 0) wmax[tid >> 6] = m;
  __syncthreads();
  if (tid == 0) {
    float mm = wmax[0];
#pragma unroll
    for (int ww = 1; ww < 16; ++ww) mm = fmaxf(mm, wmax[ww]);
    wmax[0] = mm;
  }
  __syncthreads();
  out[(size_t)g * 1024 + tid] = r / wmax[0];
}

extern "C" void kernel_launch(void* const* d_in, const int* in_sizes, int n_in,
                              void* d_out, int out_size, void* d_ws, size_t ws_size,
                              hipStream_t stream) {
  const float* x     = (const float*)d_in[0];
  const float* v     = (const float*)d_in[1];
  const float* lin   = (const float*)d_in[2];
  const int*   ei    = (const int*)d_in[3];
  const int*   face  = (const int*)d_in[4];
  const int*   batch = (const int*)d_in[5];
  const int*   scale = (const int*)d_in[6];
  const int N = in_sizes[5];
  const int E = in_sizes[3] / 2;
  const int F = in_sizes[4] / 3;
  const int M = N + E + F;
  const int nchunk = (M + CHUNK - 1) / CHUNK;

  float* nh      = (float*)d_ws;                       // N*32 f32
  int*   partial = (int*)(nh + (size_t)N * 32);        // 2*nchunk*8192 ints
  int*   part2   = partial + (size_t)2 * nchunk * 8192;  // RSL*16384 ints

  nh_kernel<<<(N + 255) / 256, 256, 0, stream>>>(x, v, nh, N);
  ect_kernel<<<2 * nchunk, 256, 0, stream>>>(nh, ei, face, batch, lin, scale,
                                             partial, N, E, F, M);
  reduce_kernel<<<64 * RSL, 256, 0, stream>>>(partial, part2, nchunk);
  fin_kernel<<<8, 1024, 0, stream>>>(part2, (float*)d_out);
}